// Round 2
// baseline (102.292 us; speedup 1.0000x reference)
//
#include <hip/hip_runtime.h>
#include <stdint.h>

// SpikingKWTA analytical collapse (verified round 1, absmax 0.0):
//   potentials stay exactly 0.0f after every step => spk == bincount(ids),
//   final pot == 0 => values = spk*1e6; lax.top_k tie-break = lowest index.
//   Key (count<<32)|(0xFFFFFFFF - v): max-order == (count desc, index asc).
//   gains[v] = count ? 0.6 : 1.0; gains[top5] = 1.5. L>=1 => fallback dead.
//
// This round: 2 dispatches (was 4).
//   K1 hist: tagged-u64 CAS histogram -- valid iff high 44 bits == MAGIC, so
//      counts need NO zeroing pass and are correct for ANY initial ws state
//      (poison 0xAA.., zeros, or garbage; false tag ~ 2^-44). Also zeroes the
//      ticket for K2 (stream order guarantees visibility).
//   K2 gains: gains write + per-block top5 (wave shfl reduce) + last-block
//      global top5 & 1.5 fixups (device-scope ticket + threadfences -- safe
//      under undefined dispatch order, no co-residency assumption).

typedef unsigned long long u64;

#define K_WIN 5
#define TB 256
#define TAG_SHIFT 20
#define TAG_MAGIC 0x5EEDFACE5Bull   // 39-bit magic; tag field is 44 bits

static __device__ __forceinline__ u64 u64max(u64 a, u64 b) { return a > b ? a : b; }

__global__ void hist_kernel(const int* __restrict__ ids, u64* __restrict__ counts,
                            uint32_t* __restrict__ ticket, int L) {
    if (blockIdx.x == 0 && threadIdx.x == 0) *ticket = 0u;  // for K2 (stream-ordered)
    int t = blockIdx.x * blockDim.x + threadIdx.x;
    int i0 = t * 4;
    int idv[4];
    int n = 0;
    if (i0 + 3 < L) {
        int4 w = *reinterpret_cast<const int4*>(ids + i0);
        idv[0] = w.x; idv[1] = w.y; idv[2] = w.z; idv[3] = w.w;
        n = 4;
    } else {
        for (; i0 + n < L && n < 4; ++n) idv[n] = ids[i0 + n];
    }
    for (int j = 0; j < n; ++j) {
        u64* p = &counts[idv[j]];
        u64 old = *p;
        for (;;) {
            u64 want = ((old >> TAG_SHIFT) == TAG_MAGIC)
                           ? (old + 1ull)
                           : ((TAG_MAGIC << TAG_SHIFT) | 1ull);
            u64 got = atomicCAS(p, old, want);
            if (got == old) break;
            old = got;
        }
    }
}

__global__ void gains_kernel(const u64* __restrict__ counts,
                             float* __restrict__ gains,
                             u64* __restrict__ cand,
                             uint32_t* __restrict__ ticket,
                             int V, int nblk) {
    const int tid = threadIdx.x;
    const int lane = tid & 63, wid = tid >> 6;
    const int v = blockIdx.x * TB + tid;

    u64 mykey = 0ull;  // never wins: any valid key has low word >= 0xFFFDFFFF
    if (v < V) {
        u64 x = counts[v];
        uint32_t c = ((x >> TAG_SHIFT) == TAG_MAGIC) ? (uint32_t)(x & 0xFFFFFu) : 0u;
        gains[v] = c ? 0.6f : 1.0f;
        mykey = ((u64)c << 32) | (u64)(0xFFFFFFFFu - (uint32_t)v);
    }

    __shared__ u64 sWave[TB / 64];
    __shared__ u64 sWin;
    __shared__ int sLast;

    // per-block top-5 -> cand[blockIdx*5 .. +4]
    for (int it = 0; it < K_WIN; ++it) {
        u64 k = mykey;
        for (int off = 32; off; off >>= 1) k = u64max(k, __shfl_xor(k, off));
        if (lane == 0) sWave[wid] = k;
        __syncthreads();
        if (tid == 0) {
            u64 w = sWave[0];
            for (int i = 1; i < TB / 64; ++i) w = u64max(w, sWave[i]);
            sWin = w;
            cand[blockIdx.x * K_WIN + it] = w;   // global store
        }
        __syncthreads();
        if (mykey == sWin) mykey = 0ull;         // keys unique -> winner retires
    }

    // last-block finalize (release: gains + cand stores visible before ticket)
    __threadfence();
    if (tid == 0) {
        uint32_t old = atomicAdd(ticket, 1u);
        sLast = (old == (uint32_t)(nblk - 1));
    }
    __syncthreads();
    if (!sLast) return;
    __threadfence();                             // acquire

    // global top-5 over nblk*5 candidates (all distinct, nonzero)
    u64 loc[K_WIN] = {0ull, 0ull, 0ull, 0ull, 0ull};
    const int ncand = nblk * K_WIN;
    for (int i = tid; i < ncand; i += TB) {
        u64 k = cand[i];
        if (k > loc[K_WIN - 1]) {
            loc[K_WIN - 1] = k;
            for (int j = K_WIN - 1; j > 0 && loc[j] > loc[j - 1]; --j) {
                u64 t2 = loc[j]; loc[j] = loc[j - 1]; loc[j - 1] = t2;
            }
        }
    }
    for (int it = 0; it < K_WIN; ++it) {
        u64 k = loc[0];
        for (int off = 32; off; off >>= 1) k = u64max(k, __shfl_xor(k, off));
        if (lane == 0) sWave[wid] = k;
        __syncthreads();
        if (tid == 0) {
            u64 w = sWave[0];
            for (int i = 1; i < TB / 64; ++i) w = u64max(w, sWave[i]);
            sWin = w;
        }
        __syncthreads();
        u64 w = sWin;
        if (loc[0] == w) {  // exactly one thread holds w (disjoint strided reads)
            for (int j = 0; j < K_WIN - 1; ++j) loc[j] = loc[j + 1];
            loc[K_WIN - 1] = 0ull;
        }
        if (tid == 0) {
            uint32_t idx = 0xFFFFFFFFu - (uint32_t)(w & 0xFFFFFFFFull);
            gains[idx] = 1.5f;  // matches lax.top_k order incl. degenerate cases
        }
    }
}

extern "C" void kernel_launch(void* const* d_in, const int* in_sizes, int n_in,
                              void* d_out, int out_size, void* d_ws, size_t ws_size,
                              hipStream_t stream) {
    const int* ids = (const int*)d_in[0];   // token_ids (int32 per harness)
    const int L = in_sizes[0];              // 4096
    const int V = out_size;                 // 131072
    float* gains = (float*)d_out;

    // ws layout: [counts64: V u64][cand: nblk*5 u64][ticket: u32]
    u64* counts = (u64*)d_ws;
    const int nblk = (V + TB - 1) / TB;     // 512
    u64* cand = counts + V;
    uint32_t* ticket = (uint32_t*)(cand + (size_t)nblk * K_WIN);

    const int hist_threads = (L + 3) / 4;   // 1024
    const int hist_blocks = (hist_threads + TB - 1) / TB;  // 4
    hist_kernel<<<hist_blocks, TB, 0, stream>>>(ids, counts, ticket, L);
    gains_kernel<<<nblk, TB, 0, stream>>>(counts, gains, cand, ticket, V, nblk);
}

// Round 6
// 71.280 us; speedup vs baseline: 1.4351x; 1.4351x over previous
//
#include <hip/hip_runtime.h>
#include <stdint.h>

// SpikingKWTA analytical collapse (verified rounds 1-2, absmax 0.0):
//   potentials stay exactly 0.0f after every step => spk == bincount(ids),
//   final pot == 0 => values = spk*1e6; lax.top_k tie-break = lowest index.
//   Key (count<<32)|(0xFFFFFFFF - v): max-order == (count desc, index asc).
//   gains[v] = count ? 0.6 : 1.0; gains[top5] = 1.5. L>=1 => fallback dead.
//
// Round 6 = round 3/4/5 resubmit (three GPU-acquisition timeouts; never ran).
// ONE dispatch, ONE block. <=4096 distinct ids => LDS hash table (8192
// slots, open addressing) holds the entire histogram. Phases ordered by
// workgroup __syncthreads only (round-2 lesson: per-wave agent-scope
// __threadfence = L2 wb/inv serialization, 43us for 1MB of traffic):
//   A) hash-hist of ids (LDS atomics)
//   B) gains[:] = 1.0 (float4 stores)
//   C) per occupied slot: gains[id] = 0.6; local top-5 keys
//   D) block top-5 reduce (shfl butterfly, keys unique) -> gains[top5] = 1.5
//   E) degenerate (<5 distinct) fallback, serial thread 0 (dead for bench)

typedef unsigned long long u64;

#define TB 1024
#define HSZ 8192
#define HMASK (HSZ - 1)
#define K_WIN 5

static __device__ __forceinline__ uint32_t hashf(uint32_t x) {
    return (x * 2654435761u) >> 19;  // top 13 bits
}
static __device__ __forceinline__ u64 u64max(u64 a, u64 b) { return a > b ? a : b; }

__global__ __launch_bounds__(TB) void kwta_kernel(const int* __restrict__ ids,
                                                  float* __restrict__ gains,
                                                  int L, int V) {
    __shared__ uint32_t sid[HSZ];   // 0 = empty, else id+1
    __shared__ uint32_t scnt[HSZ];
    __shared__ u64 sWave[TB / 64];
    __shared__ u64 sWin;

    const int tid = threadIdx.x;
    const int lane = tid & 63, wid = tid >> 6;

    for (int i = tid; i < HSZ; i += TB) { sid[i] = 0u; scnt[i] = 0u; }
    __syncthreads();

    // --- Phase A: histogram into LDS hash ---
    for (int i0 = tid * 4; i0 < L; i0 += TB * 4) {
        int idv[4];
        int n = 0;
        if (i0 + 3 < L) {
            int4 w = *reinterpret_cast<const int4*>(ids + i0);
            idv[0] = w.x; idv[1] = w.y; idv[2] = w.z; idv[3] = w.w;
            n = 4;
        } else {
            for (; i0 + n < L && n < 4; ++n) idv[n] = ids[i0 + n];
        }
        for (int j = 0; j < n; ++j) {
            uint32_t id = (uint32_t)idv[j];
            uint32_t s = hashf(id) & HMASK;
            for (;;) {
                uint32_t cur = sid[s];
                if (cur == id + 1u) { atomicAdd(&scnt[s], 1u); break; }
                if (cur == 0u) {
                    uint32_t got = atomicCAS(&sid[s], 0u, id + 1u);
                    if (got == 0u || got == id + 1u) { atomicAdd(&scnt[s], 1u); break; }
                }
                s = (s + 1) & HMASK;
            }
        }
    }

    // --- Phase B: gains[:] = 1.0 (independent of hash; no barrier needed yet) ---
    const float4 one4 = make_float4(1.f, 1.f, 1.f, 1.f);
    float4* g4 = reinterpret_cast<float4*>(gains);
    const int V4 = V >> 2;
    for (int i = tid; i < V4; i += TB) g4[i] = one4;
    for (int i = (V4 << 2) + tid; i < V; i += TB) gains[i] = 1.0f;  // tail (dead: V%4==0)

    __syncthreads();  // hash complete + 1.0 stores drained before 0.6 overwrites

    // --- Phase C: scatter 0.6 and build local top-5 (keys unique per slot) ---
    u64 loc[K_WIN] = {0ull, 0ull, 0ull, 0ull, 0ull};
    for (int s = tid; s < HSZ; s += TB) {
        uint32_t idp1 = sid[s];
        if (idp1) {
            uint32_t id = idp1 - 1u;
            uint32_t c = scnt[s];
            gains[id] = 0.6f;
            u64 key = ((u64)c << 32) | (u64)(0xFFFFFFFFu - id);
            if (key > loc[K_WIN - 1]) {
                loc[K_WIN - 1] = key;
                for (int j = K_WIN - 1; j > 0 && loc[j] > loc[j - 1]; --j) {
                    u64 t = loc[j]; loc[j] = loc[j - 1]; loc[j - 1] = t;
                }
            }
        }
    }
    __syncthreads();  // 0.6 stores drained before 1.5 overwrites

    // --- Phase D: block top-5 extraction; thread 0 applies 1.5 ---
    int nz = 0;  // meaningful on thread 0 only
    for (int it = 0; it < K_WIN; ++it) {
        u64 k = loc[0];
        for (int off = 32; off; off >>= 1) k = u64max(k, __shfl_xor(k, off));
        if (lane == 0) sWave[wid] = k;
        __syncthreads();
        if (tid == 0) {
            u64 w = sWave[0];
            for (int i = 1; i < TB / 64; ++i) w = u64max(w, sWave[i]);
            sWin = w;
        }
        __syncthreads();
        u64 w = sWin;
        if (w && loc[0] == w) {  // unique key -> exactly one holder retires it
            for (int j = 0; j < K_WIN - 1; ++j) loc[j] = loc[j + 1];
            loc[K_WIN - 1] = 0ull;
        }
        if (tid == 0 && w) {
            gains[0xFFFFFFFFu - (uint32_t)(w & 0xFFFFFFFFull)] = 1.5f;
            ++nz;
        }
        __syncthreads();  // sWave reuse hazard between iterations
    }

    // --- Phase E: degenerate fallback (<5 distinct ids) -- dead for bench ---
    if (tid == 0 && nz < K_WIN) {
        // all count>0 ids are already winners; remaining picks are the
        // lowest-index zero-count entries (lax.top_k tie order).
        int need = K_WIN - nz;
        for (uint32_t v = 0; need > 0 && v < (uint32_t)V; ++v) {
            uint32_t s = hashf(v) & HMASK;
            uint32_t c = 0u;
            for (;;) {
                uint32_t cur = sid[s];
                if (cur == 0u) break;
                if (cur == v + 1u) { c = scnt[s]; break; }
                s = (s + 1) & HMASK;
            }
            if (c == 0u) { gains[v] = 1.5f; --need; }
        }
    }
}

extern "C" void kernel_launch(void* const* d_in, const int* in_sizes, int n_in,
                              void* d_out, int out_size, void* d_ws, size_t ws_size,
                              hipStream_t stream) {
    const int* ids = (const int*)d_in[0];   // token_ids (int32 per harness)
    const int L = in_sizes[0];              // 4096
    const int V = out_size;                 // 131072
    float* gains = (float*)d_out;
    kwta_kernel<<<1, TB, 0, stream>>>(ids, gains, L, V);
}